// Round 17
// baseline (497.585 us; speedup 1.0000x reference)
//
#include <hip/hip_runtime.h>

#define N_NODES 100000
#define EDGES   1600000
#define SCAN_NB ((N_NODES + 511) / 512)   // 196 scan blocks

// ---- bf16 helpers ----------------------------------------------------------
__device__ __forceinline__ float bflo(unsigned p) { return __uint_as_float(p << 16); }
__device__ __forceinline__ float bfhi(unsigned p) { return __uint_as_float(p & 0xffff0000u); }
__device__ __forceinline__ unsigned short f2bf(float x) { return (unsigned short)((__float_as_uint(x) + 0x8000u) >> 16); }

// within-wave LDS producer->consumer fence (waves independent; no __syncthreads)
#define WAVE_FENCE() asm volatile("s_waitcnt lgkmcnt(0)" ::: "memory")

// ---------------- prep: x -> bf16 copy  +  dst histogram (fused) ------------
__global__ __launch_bounds__(256) void prep_kernel(
    const float* __restrict__ x, const int* __restrict__ ei,
    unsigned short* __restrict__ xb, int* __restrict__ cnt)
{
    int t = blockIdx.x * 256 + threadIdx.x;
    if (t < N_NODES * 32) xb[t] = f2bf(x[t]);
    if (t < EDGES) atomicAdd(&cnt[ei[EDGES + t]], 1);
}

// ---------------- exclusive scan over cnt[N] (3 kernels) -------------------
__global__ __launch_bounds__(512) void scan1_kernel(
    const int* __restrict__ cnt, int* __restrict__ part, int* __restrict__ bsum)
{
    __shared__ int s[512];
    int tid = threadIdx.x;
    int gid = blockIdx.x * 512 + tid;
    int v = (gid < N_NODES) ? cnt[gid] : 0;
    s[tid] = v;
    __syncthreads();
    for (int off = 1; off < 512; off <<= 1) {
        int t = (tid >= off) ? s[tid - off] : 0;
        __syncthreads();
        s[tid] += t;
        __syncthreads();
    }
    if (gid < N_NODES) part[gid] = s[tid] - v;
    if (tid == 511) bsum[blockIdx.x] = s[511];
}

__global__ __launch_bounds__(256) void scan2_kernel(
    const int* __restrict__ bsum, int* __restrict__ bsumx)
{
    __shared__ int s[256];
    int tid = threadIdx.x;
    int v = (tid < SCAN_NB) ? bsum[tid] : 0;
    s[tid] = v;
    __syncthreads();
    for (int off = 1; off < 256; off <<= 1) {
        int t = (tid >= off) ? s[tid - off] : 0;
        __syncthreads();
        s[tid] += t;
        __syncthreads();
    }
    bsumx[tid] = s[tid] - v;
}

__global__ __launch_bounds__(512) void scan3_kernel(
    const int* __restrict__ part, const int* __restrict__ bsumx,
    int* __restrict__ offs, int* __restrict__ cursor)
{
    int gid = blockIdx.x * 512 + threadIdx.x;
    if (gid < N_NODES) {
        int o = part[gid] + bsumx[blockIdx.x];
        offs[gid] = o;
        cursor[gid] = o;
    }
    if (gid == 0) offs[N_NODES] = EDGES;
}

// ------- CSR fill: bucket[pos] = (src<<6 byte-offset, weight bits) ---------
__global__ __launch_bounds__(256) void fill_kernel(
    const int* __restrict__ ei, const float* __restrict__ ew,
    int* __restrict__ cursor, uint2* __restrict__ bucket)
{
    int e = blockIdx.x * 256 + threadIdx.x;
    if (e >= EDGES) return;
    int d = ei[EDGES + e];
    int pos = atomicAdd(&cursor[d], 1);
    uint2 slot;
    slot.x = ((unsigned)ei[e]) << 6;    // xb row byte offset; <<1 more for h1b
    slot.y = __float_as_uint(ew[e]);
    bucket[pos] = slot;
}

// ------- layer 1: barrier-free, 1 node/wave, 4 edges/wave-load (uint) ------
__global__ __launch_bounds__(256, 8) void agg_dense1_kernel(
    const float* __restrict__ x, const unsigned short* __restrict__ xb,
    const uint2* __restrict__ bucket, const int* __restrict__ offs,
    const float* __restrict__ W_rel, const float* __restrict__ b_rel,
    const float* __restrict__ W_root, unsigned short* __restrict__ h1b)
{
    __shared__ float wrel1[32][64];    // fp32 transposed: w[k][h]
    __shared__ float wroot1[32][64];
    __shared__ float sb[64];
    __shared__ __align__(16) float accr[4][32];
    __shared__ __align__(16) float xr[4][32];
    int tid = threadIdx.x;
    for (int i = tid; i < 32 * 64; i += 256) {
        int k = i >> 6, h = i & 63;
        wrel1[k][h]  = W_rel[h * 32 + k];
        wroot1[k][h] = W_root[h * 32 + k];
    }
    if (tid < 64) sb[tid] = b_rel[tid];
    __syncthreads();          // weights visible; ONLY barrier

    const char* xcb = (const char*)xb;
    int w = tid >> 6, lane = tid & 63;
    int qsub = lane >> 4, f2 = lane & 15;    // quarter-wave: 4 edges/load
    int voff = f2 << 2;
    int wid = blockIdx.x * 4 + w;

    for (int node = wid; node < N_NODES; node += gridDim.x * 4) {
        float acc0 = 0.f, acc1 = 0.f;
        if (lane < 32) xr[w][lane] = x[(size_t)node * 32 + lane];
        int o0 = __builtin_amdgcn_readfirstlane(offs[node]);
        int o1 = __builtin_amdgcn_readfirstlane(offs[node + 1]);
        int j = o0;
        for (; j + 16 <= o1; j += 16) {
            uint2 b0 = bucket[j + 0  + qsub];
            uint2 b1 = bucket[j + 4  + qsub];
            uint2 b2 = bucket[j + 8  + qsub];
            uint2 b3 = bucket[j + 12 + qsub];
            unsigned p0 = *(const unsigned*)(xcb + (b0.x + voff));
            unsigned p1 = *(const unsigned*)(xcb + (b1.x + voff));
            unsigned p2 = *(const unsigned*)(xcb + (b2.x + voff));
            unsigned p3 = *(const unsigned*)(xcb + (b3.x + voff));
            float w0 = __uint_as_float(b0.y), w1 = __uint_as_float(b1.y);
            float w2 = __uint_as_float(b2.y), w3 = __uint_as_float(b3.y);
            acc0 += bflo(p0) * w0 + bflo(p1) * w1 + bflo(p2) * w2 + bflo(p3) * w3;
            acc1 += bfhi(p0) * w0 + bfhi(p1) * w1 + bfhi(p2) * w2 + bfhi(p3) * w3;
        }
        for (; j < o1; j += 4) {
            int jj = j + qsub;
            uint2 b = bucket[jj < o1 ? jj : (o1 - 1)];
            float wt = (jj < o1) ? __uint_as_float(b.y) : 0.f;
            unsigned p = *(const unsigned*)(xcb + (b.x + voff));
            acc0 += bflo(p) * wt;
            acc1 += bfhi(p) * wt;
        }
        acc0 += __shfl_xor(acc0, 16); acc0 += __shfl_xor(acc0, 32);
        acc1 += __shfl_xor(acc1, 16); acc1 += __shfl_xor(acc1, 32);
        if (lane < 16) {
            accr[w][2 * f2]     = acc0;
            accr[w][2 * f2 + 1] = acc1;
        }
        WAVE_FENCE();
        // phase B: h = lane; fp32 weights, uniform float2 broadcasts
        {
            const float* ap = accr[w];
            const float* xp = xr[w];
            float sum = sb[lane];
            #pragma unroll
            for (int k = 0; k < 32; k += 2) {
                float2 a  = *(const float2*)&ap[k];
                float2 xv = *(const float2*)&xp[k];
                sum += a.x  * wrel1[k][lane]  + a.y  * wrel1[k + 1][lane]
                     + xv.x * wroot1[k][lane] + xv.y * wroot1[k + 1][lane];
            }
            h1b[(size_t)node * 64 + lane] = f2bf(fmaxf(sum, 0.f));
        }
        WAVE_FENCE();         // reads done before next iteration overwrites
    }
}

// ------- layer 2: barrier-free, 1 node/wave, 2 edges/wave-load (uint) ------
__global__ __launch_bounds__(256, 4) void agg_dense2_kernel(
    const unsigned short* __restrict__ h1b, const uint2* __restrict__ bucket,
    const int* __restrict__ offs,
    const float* __restrict__ W_rel, const float* __restrict__ b_rel,
    const float* __restrict__ W_root,
    const float* __restrict__ fc_w, const float* __restrict__ fc_b,
    float* __restrict__ out)
{
    __shared__ float wrel2[64][64];    // fp32 transposed: w[k][h]  (16 KB)
    __shared__ float wroot2[64][64];   // 16 KB
    __shared__ unsigned pkfc[32][10];  // fc stays packed (tiny)
    __shared__ float sb[64], sfb[10];
    __shared__ __align__(16) float accr[4][64];
    __shared__ __align__(16) float hvr[4][64];
    __shared__ __align__(16) float sh2r[4][64];
    int tid = threadIdx.x;
    for (int i = tid; i < 64 * 64; i += 256) {
        int k = i >> 6, h = i & 63;
        wrel2[k][h]  = W_rel[h * 64 + k];
        wroot2[k][h] = W_root[h * 64 + k];
    }
    for (int i = tid; i < 32 * 10; i += 256) {
        int k = i % 32, c = i / 32;
        unsigned lo = (__float_as_uint(fc_w[c * 64 + 2 * k]) + 0x8000u) >> 16;
        unsigned hi = (__float_as_uint(fc_w[c * 64 + 2 * k + 1]) + 0x8000u) & 0xffff0000u;
        pkfc[k][c] = hi | lo;
    }
    if (tid < 64) sb[tid] = b_rel[tid];
    if (tid < 10) sfb[tid] = fc_b[tid];
    __syncthreads();          // ONLY barrier

    const char* h1cb = (const char*)h1b;
    int w = tid >> 6, lane = tid & 63;
    int sub = lane >> 5, f2 = lane & 31;     // half-wave: 2 edges/load
    int voff = f2 << 2;
    int wid = blockIdx.x * 4 + w;

    for (int node = wid; node < N_NODES; node += gridDim.x * 4) {
        float acc0 = 0.f, acc1 = 0.f;
        if (sub == 0) {
            unsigned hp = *(const unsigned*)(h1cb + (((unsigned)node << 7) + voff));
            hvr[w][2 * f2]     = bflo(hp);
            hvr[w][2 * f2 + 1] = bfhi(hp);
        }
        int o0 = __builtin_amdgcn_readfirstlane(offs[node]);
        int o1 = __builtin_amdgcn_readfirstlane(offs[node + 1]);
        int j = o0;
        for (; j + 16 <= o1; j += 16) {
            uint2 b0 = bucket[j + 0  + sub];
            uint2 b1 = bucket[j + 2  + sub];
            uint2 b2 = bucket[j + 4  + sub];
            uint2 b3 = bucket[j + 6  + sub];
            uint2 b4 = bucket[j + 8  + sub];
            uint2 b5 = bucket[j + 10 + sub];
            uint2 b6 = bucket[j + 12 + sub];
            uint2 b7 = bucket[j + 14 + sub];
            unsigned p0 = *(const unsigned*)(h1cb + ((b0.x << 1) + voff));
            unsigned p1 = *(const unsigned*)(h1cb + ((b1.x << 1) + voff));
            unsigned p2 = *(const unsigned*)(h1cb + ((b2.x << 1) + voff));
            unsigned p3 = *(const unsigned*)(h1cb + ((b3.x << 1) + voff));
            unsigned p4 = *(const unsigned*)(h1cb + ((b4.x << 1) + voff));
            unsigned p5 = *(const unsigned*)(h1cb + ((b5.x << 1) + voff));
            unsigned p6 = *(const unsigned*)(h1cb + ((b6.x << 1) + voff));
            unsigned p7 = *(const unsigned*)(h1cb + ((b7.x << 1) + voff));
            float w0 = __uint_as_float(b0.y), w1 = __uint_as_float(b1.y);
            float w2 = __uint_as_float(b2.y), w3 = __uint_as_float(b3.y);
            float w4 = __uint_as_float(b4.y), w5 = __uint_as_float(b5.y);
            float w6 = __uint_as_float(b6.y), w7 = __uint_as_float(b7.y);
            acc0 += bflo(p0) * w0 + bflo(p1) * w1 + bflo(p2) * w2 + bflo(p3) * w3
                  + bflo(p4) * w4 + bflo(p5) * w5 + bflo(p6) * w6 + bflo(p7) * w7;
            acc1 += bfhi(p0) * w0 + bfhi(p1) * w1 + bfhi(p2) * w2 + bfhi(p3) * w3
                  + bfhi(p4) * w4 + bfhi(p5) * w5 + bfhi(p6) * w6 + bfhi(p7) * w7;
        }
        for (; j < o1; j += 2) {
            int jj = j + sub;
            uint2 b = bucket[jj < o1 ? jj : (o1 - 1)];
            float wt = (jj < o1) ? __uint_as_float(b.y) : 0.f;
            unsigned p = *(const unsigned*)(h1cb + ((b.x << 1) + voff));
            acc0 += bflo(p) * wt;
            acc1 += bfhi(p) * wt;
        }
        acc0 += __shfl_xor(acc0, 32);
        acc1 += __shfl_xor(acc1, 32);
        if (sub == 0) {
            accr[w][2 * f2]     = acc0;
            accr[w][2 * f2 + 1] = acc1;
        }
        WAVE_FENCE();
        // phase B: relu dense, h = lane; fp32 weights
        {
            const float* ap = accr[w];
            const float* hp = hvr[w];
            float sum = sb[lane];
            #pragma unroll
            for (int k = 0; k < 64; k += 2) {
                float2 a  = *(const float2*)&ap[k];
                float2 h2 = *(const float2*)&hp[k];
                sum += a.x  * wrel2[k][lane]  + a.y  * wrel2[k + 1][lane]
                     + h2.x * wroot2[k][lane] + h2.y * wroot2[k + 1][lane];
            }
            sh2r[w][lane] = fmaxf(sum, 0.f);
        }
        WAVE_FENCE();
        // phase C: fc on 10 lanes
        if (lane < 10) {
            const float2* sp = (const float2*)sh2r[w];
            float o = sfb[lane];
            #pragma unroll
            for (int k = 0; k < 32; ++k) {
                float2 s2 = sp[k];
                unsigned pc = pkfc[k][lane];
                o += s2.x * bflo(pc) + s2.y * bfhi(pc);
            }
            out[(size_t)node * 10 + lane] = o;
        }
        WAVE_FENCE();         // sh2r reads done before next iteration writes
    }
}

extern "C" void kernel_launch(void* const* d_in, const int* in_sizes, int n_in,
                              void* d_out, int out_size, void* d_ws, size_t ws_size,
                              hipStream_t stream) {
    const float* x       = (const float*)d_in[0];
    const int*   ei      = (const int*)d_in[1];     // [2, E] int32
    const float* ew      = (const float*)d_in[2];
    const float* W1_rel  = (const float*)d_in[3];
    const float* b1_rel  = (const float*)d_in[4];
    const float* W1_root = (const float*)d_in[5];
    const float* W2_rel  = (const float*)d_in[6];
    const float* b2_rel  = (const float*)d_in[7];
    const float* W2_root = (const float*)d_in[8];
    const float* fc_w    = (const float*)d_in[9];
    const float* fc_b    = (const float*)d_in[10];
    float* out = (float*)d_out;

    // workspace layout (~34 MB)
    uint2* bucket       = (uint2*)d_ws;                          // E (12.8 MB)
    unsigned short* h1b = (unsigned short*)(bucket + EDGES);     // N*64 bf16 (12.8 MB)
    unsigned short* xb  = h1b + (size_t)N_NODES * 64;            // N*32 bf16 (6.4 MB)
    int*   cnt    = (int*)(xb + (size_t)N_NODES * 32);           // N
    int*   part   = cnt + N_NODES;                               // N
    int*   offs   = part + N_NODES;                              // N+1
    int*   cursor = offs + N_NODES + 1;                          // N
    int*   bsum   = cursor + N_NODES;                            // 256
    int*   bsumx  = bsum + 256;                                  // 256

    hipMemsetAsync(cnt, 0, (size_t)N_NODES * sizeof(int), stream);

    prep_kernel<<<(N_NODES * 32 + 255) / 256, 256, 0, stream>>>(x, ei, xb, cnt);
    scan1_kernel<<<SCAN_NB, 512, 0, stream>>>(cnt, part, bsum);
    scan2_kernel<<<1, 256, 0, stream>>>(bsum, bsumx);
    scan3_kernel<<<SCAN_NB, 512, 0, stream>>>(part, bsumx, offs, cursor);
    fill_kernel<<<(EDGES + 255) / 256, 256, 0, stream>>>(ei, ew, cursor, bucket);

    agg_dense1_kernel<<<2048, 256, 0, stream>>>(
        x, xb, bucket, offs, W1_rel, b1_rel, W1_root, h1b);
    agg_dense2_kernel<<<1024, 256, 0, stream>>>(
        h1b, bucket, offs, W2_rel, b2_rel, W2_root, fc_w, fc_b, out);
}